// Round 1
// baseline (160.403 us; speedup 1.0000x reference)
//
#include <hip/hip_runtime.h>

#define N_TOTAL   16777216
#define NWIN      65536
#define NFFT      256
#define MACROS    16384      /* NWIN/4 : 4 windows per macro-iteration */
#define MIN_FREQS 202
#define MIN_TIMES 51773
#define NSLOTS    64

/* workspace layout (float indices) */
#define IDX_ABSMAX  0      /* uint bits, atomicMax */
#define IDX_TMAX    1      /* uint bits, atomicMax */
#define IDX_TMODE   2      /* int: 1 = time top-k fallback */
#define IDX_FMALL   3      /* int: 1 = freq mask all ones */
#define IDX_TTHR    4
#define IDX_INVNORM 5
#define IDX_FCNT    6
#define IDX_FMASK   8      /* 256 floats (bit-reversed freq order) */
#define IDX_SLOTS   264    /* 64*256 floats, freq-energy partial slots */
#define IDX_SUMSQ   16648  /* 65536 floats, per-window sum of squares */
#define IDX_TMASKA  82184  /* 65536 floats, time mask */

/* ---------------- K1: stats pass (sumsq, absmax, freq energy via FFT) ------ */
__global__ __launch_bounds__(256) void k_stats(const float* __restrict__ x,
                                               float* __restrict__ W)
{
    __shared__ float re[1024], im[1024];
    __shared__ float twr[128], twi[128];
    __shared__ float red[256];
    const int tid = threadIdx.x;
    if (tid < 128) {
        float s, c;
        __sincosf(-6.283185307179586f * (float)tid / 256.0f, &s, &c);
        twr[tid] = c; twi[tid] = s;           /* exp(-2*pi*i*t/256) */
    }
    float facc = 0.f, amax = 0.f, tmx = 0.f;
    float* sumsq = W + IDX_SUMSQ;
    for (int mw = blockIdx.x; mw < MACROS; mw += gridDim.x) {
        const float4 v = reinterpret_cast<const float4*>(x)[mw * 256 + tid];
        amax = fmaxf(amax, fmaxf(fmaxf(fabsf(v.x), fabsf(v.y)),
                                 fmaxf(fabsf(v.z), fabsf(v.w))));
        const int win  = tid >> 6;
        const int b    = win * 256 + ((tid & 63) << 2);
        re[b] = v.x; re[b+1] = v.y; re[b+2] = v.z; re[b+3] = v.w;
        im[b] = 0.f; im[b+1] = 0.f; im[b+2] = 0.f; im[b+3] = 0.f;
        red[tid] = v.x*v.x + v.y*v.y + v.z*v.z + v.w*v.w;
        __syncthreads();
        /* segmented (per-64-thread = per-window) sum reduce */
        for (int s = 32; s > 0; s >>= 1) {
            if ((tid & 63) < s) red[tid] += red[tid + s];
            __syncthreads();
        }
        const float ss = red[(tid >> 6) << 6];
        if ((tid & 63) == 0) sumsq[mw * 4 + win] = ss;
        tmx = fmaxf(tmx, ss);
        /* radix-2 DIF FFT, 4 windows in parallel, 2 butterflies/thread */
        for (int lh = 7; lh >= 0; lh--) {
            const int half = 1 << lh;
            #pragma unroll
            for (int bb = 0; bb < 2; bb++) {
                const int bf = tid + bb * 256;
                const int w  = bf >> 7, j = bf & 127;
                const int k  = j & (half - 1);
                const int i0 = w * 256 + (((j & ~(half - 1)) << 1) | k);
                const int i1 = i0 + half;
                const float ar = re[i0], ai = im[i0], br = re[i1], bi = im[i1];
                const float dr = ar - br, di = ai - bi;
                re[i0] = ar + br; im[i0] = ai + bi;
                const int ti = k << (7 - lh);
                const float wr = twr[ti], wi = twi[ti];
                re[i1] = dr * wr - di * wi;
                im[i1] = dr * wi + di * wr;
            }
            __syncthreads();
        }
        #pragma unroll
        for (int w = 0; w < 4; w++) {
            const float rr = re[w * 256 + tid], ii = im[w * 256 + tid];
            facc += rr * rr + ii * ii;       /* energy of bin tid (brev order) */
        }
        __syncthreads();
    }
    atomicAdd(&W[IDX_SLOTS + (blockIdx.x & (NSLOTS - 1)) * 256 + tid], facc);
    red[tid] = amax; __syncthreads();
    for (int s = 128; s > 0; s >>= 1) {
        if (tid < s) red[tid] = fmaxf(red[tid], red[tid + s]);
        __syncthreads();
    }
    if (tid == 0) atomicMax((unsigned int*)W + IDX_ABSMAX, __float_as_uint(red[0]));
    __syncthreads();
    red[tid] = tmx; __syncthreads();
    for (int s = 128; s > 0; s >>= 1) {
        if (tid < s) red[tid] = fmaxf(red[tid], red[tid + s]);
        __syncthreads();
    }
    if (tid == 0) atomicMax((unsigned int*)W + IDX_TMAX, __float_as_uint(red[0]));
}

/* ---------------- K2: masks / flags / norm (single block) ------------------ */
__global__ __launch_bounds__(256) void k_masks(float* __restrict__ W)
{
    __shared__ float e[256];
    __shared__ float red[256];
    const int tid = threadIdx.x;
    float acc = 0.f;
    for (int s = 0; s < NSLOTS; s++) acc += W[IDX_SLOTS + s * 256 + tid];
    e[tid] = acc;
    red[tid] = acc; __syncthreads();
    for (int s = 128; s > 0; s >>= 1) {
        if (tid < s) red[tid] = fmaxf(red[tid], red[tid + s]);
        __syncthreads();
    }
    const float fthr = 0.05f * red[0];
    __syncthreads();
    const int my = (acc > fthr) ? 1 : 0;
    red[tid] = (float)my; __syncthreads();
    for (int s = 128; s > 0; s >>= 1) {
        if (tid < s) red[tid] += red[tid + s];
        __syncthreads();
    }
    const int fcnt = (int)red[0];
    __syncthreads();
    float m;
    if (fcnt >= MIN_FREQS) {
        m = (float)my;
    } else {
        /* exact top-k mask; ties by ORIGINAL freq index (bins are bit-reversed) */
        const int oi = (int)(__brev((unsigned)tid) >> 24);
        int rank = 0;
        for (int j = 0; j < 256; j++) {
            const float ej = e[j];
            const int oj = (int)(__brev((unsigned)j) >> 24);
            if (ej > acc || (ej == acc && oj < oi)) rank++;
        }
        m = (rank < MIN_FREQS) ? 1.f : 0.f;
    }
    W[IDX_FMASK + tid] = m;
    red[tid] = m; __syncthreads();
    for (int s = 128; s > 0; s >>= 1) {
        if (tid < s) red[tid] += red[tid + s];
        __syncthreads();
    }
    if (tid == 0) {
        ((int*)W)[IDX_FMALL] = ((int)red[0] == 256) ? 1 : 0;
        ((int*)W)[IDX_FCNT]  = fcnt;
        const float mx = __uint_as_float(((unsigned int*)W)[IDX_ABSMAX]);
        W[IDX_INVNORM] = 1.f / ((mx > 1e-10f) ? mx : 1.f);
    }
    /* time mask: threshold path (speculative; K2b overwrites on fallback) */
    const float tmax = __uint_as_float(((unsigned int*)W)[IDX_TMAX]);
    const float tthr = 0.05f * tmax;
    const float* sumsq = W + IDX_SUMSQ;
    float* tmask = W + IDX_TMASKA;
    int c = 0;
    for (int i = tid; i < NWIN; i += 256) {
        const int mm = (sumsq[i] > tthr) ? 1 : 0;
        c += mm;
        tmask[i] = (float)mm;
    }
    __syncthreads();
    red[tid] = (float)c; __syncthreads();
    for (int s = 128; s > 0; s >>= 1) {
        if (tid < s) red[tid] += red[tid + s];
        __syncthreads();
    }
    if (tid == 0) {
        ((int*)W)[IDX_TMODE] = ((int)red[0] < MIN_TIMES) ? 1 : 0;
        W[IDX_TTHR] = tthr;
    }
}

/* ---------------- K2b: exact time top-k fallback (early-exit normally) ----- */
__global__ __launch_bounds__(256) void k_timefb(float* __restrict__ W)
{
    if (((const int*)W)[IDX_TMODE] == 0) return;
    const int t = blockIdx.x * 256 + threadIdx.x;
    const float* sumsq = W + IDX_SUMSQ;
    const float st = sumsq[t];
    int rank = 0;
    for (int j = 0; j < NWIN; j++) {
        const float sj = sumsq[j];
        if (sj > st || (sj == st && j < t)) rank++;
    }
    W[IDX_TMASKA + t] = (rank < MIN_TIMES) ? 1.f : 0.f;
}

/* ---------------- K3: output pass ------------------------------------------ */
__global__ __launch_bounds__(256) void k_out(const float* __restrict__ x,
                                             float* __restrict__ out,
                                             const float* __restrict__ W)
{
    const int tid = threadIdx.x;
    const int fm_all = ((const int*)W)[IDX_FMALL];
    const float inv_norm = W[IDX_INVNORM];
    if (fm_all) {
        /* ifft(fft(x) * 1) == x : masked scaled copy, float4 */
        const float4* xi = (const float4*)x;
        float4* yo = (float4*)out;
        const float* tmask = W + IDX_TMASKA;
        for (int i = blockIdx.x * 256 + tid; i < N_TOTAL / 4; i += gridDim.x * 256) {
            const float s = inv_norm * tmask[i >> 6];
            float4 v = xi[i];
            v.x *= s; v.y *= s; v.z *= s; v.w *= s;
            yo[i] = v;
        }
        return;
    }
    /* general path: FFT -> freq mask -> IFFT per window */
    __shared__ float re[256], im[256], twr[128], twi[128], fm[256];
    if (tid < 128) {
        float s, c;
        __sincosf(-6.283185307179586f * (float)tid / 256.0f, &s, &c);
        twr[tid] = c; twi[tid] = s;
    }
    fm[tid] = W[IDX_FMASK + tid];
    __syncthreads();
    const float scale = inv_norm * (1.f / 256.f);
    for (int w = blockIdx.x; w < NWIN; w += gridDim.x) {
        const float tm = W[IDX_TMASKA + w];
        if (tm == 0.f) { out[w * 256 + tid] = 0.f; continue; }
        re[tid] = x[w * 256 + tid]; im[tid] = 0.f;
        __syncthreads();
        for (int lh = 7; lh >= 0; lh--) {              /* DIF forward */
            const int half = 1 << lh;
            if (tid < 128) {
                const int k  = tid & (half - 1);
                const int i0 = ((tid & ~(half - 1)) << 1) | k;
                const int i1 = i0 + half;
                const float ar = re[i0], ai = im[i0], br = re[i1], bi = im[i1];
                const float dr = ar - br, di = ai - bi;
                re[i0] = ar + br; im[i0] = ai + bi;
                const int ti = k << (7 - lh);
                const float wr = twr[ti], wi = twi[ti];
                re[i1] = dr * wr - di * wi;
                im[i1] = dr * wi + di * wr;
            }
            __syncthreads();
        }
        re[tid] *= fm[tid]; im[tid] *= fm[tid];
        __syncthreads();
        for (int lh = 0; lh < 8; lh++) {               /* DIT inverse (conj) */
            const int half = 1 << lh;
            if (tid < 128) {
                const int k  = tid & (half - 1);
                const int i0 = ((tid & ~(half - 1)) << 1) | k;
                const int i1 = i0 + half;
                const int ti = k << (7 - lh);
                const float wr = twr[ti], wi = -twi[ti];
                const float br = re[i1], bi = im[i1];
                const float tr = br * wr - bi * wi;
                const float ts = br * wi + bi * wr;
                const float ar = re[i0], ai = im[i0];
                re[i1] = ar - tr; im[i1] = ai - ts;
                re[i0] = ar + tr; im[i0] = ai + ts;
            }
            __syncthreads();
        }
        out[w * 256 + tid] = re[tid] * scale;
        __syncthreads();
    }
}

extern "C" void kernel_launch(void* const* d_in, const int* in_sizes, int n_in,
                              void* d_out, int out_size, void* d_ws, size_t ws_size,
                              hipStream_t stream)
{
    const float* x = (const float*)d_in[0];
    float* out = (float*)d_out;
    float* W = (float*)d_ws;
    /* zero atomic accumulators + freq slots (0x00 == 0.0f == max-identity) */
    hipMemsetAsync(d_ws, 0, (size_t)IDX_SUMSQ * sizeof(float), stream);
    hipLaunchKernelGGL(k_stats,  dim3(2048), dim3(256), 0, stream, x, W);
    hipLaunchKernelGGL(k_masks,  dim3(1),    dim3(256), 0, stream, W);
    hipLaunchKernelGGL(k_timefb, dim3(256),  dim3(256), 0, stream, W);
    hipLaunchKernelGGL(k_out,    dim3(2048), dim3(256), 0, stream, x, out, W);
}